// Round 3
// baseline (291.075 us; speedup 1.0000x reference)
//
#include <hip/hip_runtime.h>
#include <math.h>

#define SS 32768

typedef _Float16 half4v __attribute__((ext_vector_type(4)));
typedef _Float16 half8v __attribute__((ext_vector_type(8)));
typedef float float4v __attribute__((ext_vector_type(4)));

__device__ __forceinline__ void gload16(const void* g, void* l) {
    __builtin_amdgcn_global_load_lds(
        (const __attribute__((address_space(1))) unsigned int*)g,
        (__attribute__((address_space(3))) unsigned int*)l, 16, 0, 0);
}

// ---------------------------------------------------------------------------
// K0a: x[b][c][s] fp32 -> x_t[b][s][c] fp16 (LDS tile transpose)
// ---------------------------------------------------------------------------
__global__ __launch_bounds__(256)
void cvt_x_kernel(const float* __restrict__ x, _Float16* __restrict__ x_t)
{
    __shared__ float ls[64][65];
    const int b = blockIdx.z, c0 = blockIdx.y * 64, s0 = blockIdx.x * 64;
    const int t = threadIdx.x;
    const int tr = t >> 4, tc = t & 15;
#pragma unroll
    for (int p = 0; p < 4; p++) {
        int c_l = p * 16 + tr;
        float4v v = *(const float4v*)(x + (size_t)(b * 256 + c0 + c_l) * SS + s0 + tc * 4);
        ls[c_l][tc * 4 + 0] = v.x;
        ls[c_l][tc * 4 + 1] = v.y;
        ls[c_l][tc * 4 + 2] = v.z;
        ls[c_l][tc * 4 + 3] = v.w;
    }
    __syncthreads();
#pragma unroll
    for (int p = 0; p < 4; p++) {
        int s_l = p * 16 + tr;
        half4v h;
        h.x = (_Float16)ls[tc * 4 + 0][s_l];
        h.y = (_Float16)ls[tc * 4 + 1][s_l];
        h.z = (_Float16)ls[tc * 4 + 2][s_l];
        h.w = (_Float16)ls[tc * 4 + 3][s_l];
        *(half4v*)(x_t + ((size_t)b * SS + s0 + s_l) * 256 + c0 + tc * 4) = h;
    }
}

// ---------------------------------------------------------------------------
// K0b: all three weight casts in one launch. q_w: blocks 0-127, kv_w: 128-159,
// proj_w: 160-287 (1024 elements per block).
// ---------------------------------------------------------------------------
__global__ __launch_bounds__(256)
void cvt_w3_kernel(const float* __restrict__ s0, _Float16* __restrict__ d0,
                   const float* __restrict__ s1, _Float16* __restrict__ d1,
                   const float* __restrict__ s2, _Float16* __restrict__ d2)
{
    int bx = blockIdx.x;
    const float* s; _Float16* d; int base;
    if (bx < 128)      { s = s0; d = d0; base = bx; }
    else if (bx < 160) { s = s1; d = d1; base = bx - 128; }
    else               { s = s2; d = d2; base = bx - 160; }
    int i = (base * 256 + threadIdx.x) * 4;
    float4v v = *(const float4v*)(s + i);
    half4v h;
    h.x = (_Float16)v.x; h.y = (_Float16)v.y; h.z = (_Float16)v.z; h.w = (_Float16)v.w;
    *(half4v*)(d + i) = h;
}

// ---------------------------------------------------------------------------
// K1: fused q+kv conv via MFMA, BK=64, bank-swizzled LDS.
// out_t[b,s,o] = sum_c W[o,c]*x_t[b,s,c] + bias.  128(o) x 128(s) tile.
// Block swizzle: the 5 o_tiles of one s_tile share blockIdx%8 (same XCD) so
// the x-tile is fetched from HBM once and hit in that XCD's L2 afterwards.
// LDS rows are 64 fp16 (128 B): chunk g of row r stored at slot (g+r)&7 so
// b128 fragment reads hit the uniform 8-words/bank floor.
// ---------------------------------------------------------------------------
__global__ __launch_bounds__(256)
void conv_mfma_kernel(const _Float16* __restrict__ x_t,
                      const _Float16* __restrict__ wq,
                      const _Float16* __restrict__ wkv,
                      const float* __restrict__ q_b,
                      const float* __restrict__ kv_b,
                      _Float16* __restrict__ q_t,
                      _Float16* __restrict__ kv_t)
{
    __shared__ _Float16 Ws[128 * 64];
    __shared__ _Float16 Xs[128 * 64];
    const int b = blockIdx.y;
    const int bx = blockIdx.x;
    const int grp = bx / 40, rem = bx % 40;
    const int s_tile = grp * 8 + (rem & 7);
    const int o_tile = rem >> 3;
    const int s0 = s_tile * 128;
    const bool is_q = (o_tile < 4);
    const _Float16* W = is_q ? wq : wkv;
    const float* bias = is_q ? q_b : kv_b;
    const int od0 = is_q ? o_tile * 128 : 0;
    const int ODST = is_q ? 512 : 128;
    _Float16* dst = is_q ? q_t : kv_t;

    const int t = threadIdx.x;
    const int w = t >> 6, l = t & 63;
    const int om = (w & 1) * 64, sn = (w >> 1) * 64;

    const int lr = l >> 3;                       // staging row within 8-row group
    const int gch = ((l & 7) - lr) & 7;          // global chunk this lane stages
    const int m15 = l & 15;
    const int sl0 = ((((l >> 4) + (l & 7)) & 7)) * 8;      // read slot, ks=0
    const int sl1 = ((((l >> 4) + 4 + (l & 7)) & 7)) * 8;  // read slot, ks=1

    float4v acc[4][4];
#pragma unroll
    for (int i = 0; i < 4; i++)
#pragma unroll
        for (int j = 0; j < 4; j++) acc[i][j] = (float4v){0.f, 0.f, 0.f, 0.f};

    const _Float16* wg = W + (size_t)(od0 + 32 * w + lr) * 256 + gch * 8;
    const _Float16* xg = x_t + ((size_t)b * SS + s0 + 32 * w + lr) * 256 + gch * 8;
    _Float16* wl = &Ws[(32 * w) * 64];
    _Float16* xl = &Xs[(32 * w) * 64];

    for (int c0 = 0; c0 < 256; c0 += 64) {
#pragma unroll
        for (int rb = 0; rb < 4; rb++) {
            gload16(wg + (size_t)rb * 8 * 256 + c0, wl + rb * 8 * 64);
            gload16(xg + (size_t)rb * 8 * 256 + c0, xl + rb * 8 * 64);
        }
        __syncthreads();
#pragma unroll
        for (int ks = 0; ks < 2; ks++) {
            const int sl = ks ? sl1 : sl0;
            half8v a[4], bb[4];
#pragma unroll
            for (int i = 0; i < 4; i++)
                a[i] = *(const half8v*)&Ws[(om + i * 16 + m15) * 64 + sl];
#pragma unroll
            for (int j = 0; j < 4; j++)
                bb[j] = *(const half8v*)&Xs[(sn + j * 16 + m15) * 64 + sl];
#pragma unroll
            for (int i = 0; i < 4; i++)
#pragma unroll
                for (int j = 0; j < 4; j++)
                    acc[i][j] = __builtin_amdgcn_mfma_f32_16x16x32_f16(a[i], bb[j], acc[i][j], 0, 0, 0);
        }
        __syncthreads();
    }
    const int qd = l >> 4, m = l & 15;
#pragma unroll
    for (int i = 0; i < 4; i++) {
        float bv[4];
#pragma unroll
        for (int r = 0; r < 4; r++) bv[r] = bias[od0 + om + i * 16 + qd * 4 + r];
#pragma unroll
        for (int j = 0; j < 4; j++) {
            half4v h;
            h.x = (_Float16)(acc[i][j].x + bv[0]);
            h.y = (_Float16)(acc[i][j].y + bv[1]);
            h.z = (_Float16)(acc[i][j].z + bv[2]);
            h.w = (_Float16)(acc[i][j].w + bv[3]);
            size_t s = (size_t)b * SS + s0 + sn + j * 16 + m;
            *(half4v*)(dst + s * ODST + od0 + om + i * 16 + qd * 4) = h;
        }
    }
}

// ---------------------------------------------------------------------------
// K2: logits, no LDS staging, no K-loop barriers. Each wave takes 8 hw slices;
// A/B fragments loaded straight from global in MFMA layout (lane&15 row,
// (lane>>4)*8 chunk). Per-block partial 32x32 tile reduced via LDS, written
// to Lpart[hwc][b][nh][32*32] (softmax reduces over hwc).
// ---------------------------------------------------------------------------
__global__ __launch_bounds__(256)
void logits_kernel(const _Float16* __restrict__ q_t,
                   const _Float16* __restrict__ kv_t,
                   float* __restrict__ Lpart)
{
    __shared__ float red[4][1024];
    const int hwc = blockIdx.x, nh = blockIdx.y, b = blockIdx.z;
    const int t = threadIdx.x, w = t >> 6, l = t & 63;
    const int m = l & 15, c8 = (l >> 4) * 8;
    float4v acc[2][2];
#pragma unroll
    for (int i = 0; i < 2; i++)
#pragma unroll
        for (int j = 0; j < 2; j++) acc[i][j] = (float4v){0.f, 0.f, 0.f, 0.f};

    const _Float16* qb0 = q_t + (size_t)b * SS * 512 + nh * 64 + c8;
    const _Float16* kb0 = kv_t + (size_t)b * SS * 128 + c8;
#pragma unroll 4
    for (int hh = 0; hh < 8; hh++) {
        const int hw = hwc * 32 + w * 8 + hh;
        const _Float16* qr0 = qb0 + ((size_t)m * 1024 + hw) * 512;
        const _Float16* qr1 = qb0 + ((size_t)(m + 16) * 1024 + hw) * 512;
        const _Float16* kr0 = kb0 + ((size_t)m * 1024 + hw) * 128;
        const _Float16* kr1 = kb0 + ((size_t)(m + 16) * 1024 + hw) * 128;
        half8v a0l = *(const half8v*)(qr0);
        half8v a0h = *(const half8v*)(qr0 + 32);
        half8v a1l = *(const half8v*)(qr1);
        half8v a1h = *(const half8v*)(qr1 + 32);
        half8v b0l = *(const half8v*)(kr0);
        half8v b0h = *(const half8v*)(kr0 + 32);
        half8v b1l = *(const half8v*)(kr1);
        half8v b1h = *(const half8v*)(kr1 + 32);
        acc[0][0] = __builtin_amdgcn_mfma_f32_16x16x32_f16(a0l, b0l, acc[0][0], 0, 0, 0);
        acc[0][0] = __builtin_amdgcn_mfma_f32_16x16x32_f16(a0h, b0h, acc[0][0], 0, 0, 0);
        acc[0][1] = __builtin_amdgcn_mfma_f32_16x16x32_f16(a0l, b1l, acc[0][1], 0, 0, 0);
        acc[0][1] = __builtin_amdgcn_mfma_f32_16x16x32_f16(a0h, b1h, acc[0][1], 0, 0, 0);
        acc[1][0] = __builtin_amdgcn_mfma_f32_16x16x32_f16(a1l, b0l, acc[1][0], 0, 0, 0);
        acc[1][0] = __builtin_amdgcn_mfma_f32_16x16x32_f16(a1h, b0h, acc[1][0], 0, 0, 0);
        acc[1][1] = __builtin_amdgcn_mfma_f32_16x16x32_f16(a1l, b1l, acc[1][1], 0, 0, 0);
        acc[1][1] = __builtin_amdgcn_mfma_f32_16x16x32_f16(a1h, b1h, acc[1][1], 0, 0, 0);
    }
    const int rbase = (l >> 4) * 4;
#pragma unroll
    for (int qi = 0; qi < 2; qi++)
#pragma unroll
        for (int qj = 0; qj < 2; qj++)
#pragma unroll
            for (int rr = 0; rr < 4; rr++)
                red[w][(qi * 16 + rbase + rr) * 32 + qj * 16 + m] = acc[qi][qj][rr];
    __syncthreads();
    float4v v = *(const float4v*)&red[0][t * 4];
    v += *(const float4v*)&red[1][t * 4];
    v += *(const float4v*)&red[2][t * 4];
    v += *(const float4v*)&red[3][t * 4];
    *(float4v*)(Lpart + (((size_t)hwc * 2 + b) * 8 + nh) * 1024 + t * 4) = v;
}

// ---------------------------------------------------------------------------
// K3: reduce 32 hwc partials + softmax (scale 0.125), write dense Lsm.
// ---------------------------------------------------------------------------
__global__ __launch_bounds__(256)
void softmax_kernel(const float* __restrict__ Lpart, float* __restrict__ Lsm)
{
    int r = blockIdx.x * 256 + threadIdx.x;   // 0..511 = (b, nh, d)
    float4v p[8];
#pragma unroll
    for (int j4 = 0; j4 < 8; j4++) p[j4] = (float4v){0.f, 0.f, 0.f, 0.f};
    for (int hwc = 0; hwc < 32; hwc++) {
        const float* src = Lpart + (size_t)hwc * 16384 + (size_t)r * 32;
#pragma unroll
        for (int j4 = 0; j4 < 8; j4++) p[j4] += *(const float4v*)(src + j4 * 4);
    }
    float mx = p[0].x;
#pragma unroll
    for (int j4 = 0; j4 < 8; j4++) {
        mx = fmaxf(mx, p[j4].x); mx = fmaxf(mx, p[j4].y);
        mx = fmaxf(mx, p[j4].z); mx = fmaxf(mx, p[j4].w);
    }
    float s = 0.f;
#pragma unroll
    for (int j4 = 0; j4 < 8; j4++) {
        p[j4].x = expf((p[j4].x - mx) * 0.125f); s += p[j4].x;
        p[j4].y = expf((p[j4].y - mx) * 0.125f); s += p[j4].y;
        p[j4].z = expf((p[j4].z - mx) * 0.125f); s += p[j4].z;
        p[j4].w = expf((p[j4].w - mx) * 0.125f); s += p[j4].w;
    }
    float inv = 1.f / s;
    float* dst = Lsm + (size_t)r * 32;
#pragma unroll
    for (int j4 = 0; j4 < 8; j4++) {
        float4v o = p[j4];
        o.x *= inv; o.y *= inv; o.z *= inv; o.w *= inv;
        *(float4v*)(dst + j4 * 4) = o;
    }
}

// ---------------------------------------------------------------------------
// K4: o_t[b, s'=(d,h,w), c'] = sum_j attn[b, h>>3.., ...] (torch-exact reorder)
// ---------------------------------------------------------------------------
__global__ __launch_bounds__(256)
void attn_v_kernel(const _Float16* __restrict__ kv_t,
                   const float* __restrict__ attn,
                   _Float16* __restrict__ o_t)
{
    __shared__ float as_[8 * 32 * 32];
    const int wq = blockIdx.x, hl = blockIdx.y, b = blockIdx.z;
    const int t = threadIdx.x;
    {
        const float* src = attn + (size_t)b * 8192;
#pragma unroll
        for (int ll = 0; ll < 8; ll++) {
            int idx = (t + ll * 256) * 4;
            *(float4v*)(&as_[idx]) = *(const float4v*)(src + idx);
        }
    }
    __syncthreads();
    const int q4 = t & 127;
    const int half = t >> 7;
    const int tt = q4 >> 4;
    const int vd = (q4 * 4) & 63;
    const int hw = hl * 256 + wq * 8 + tt;
    float4v vreg[32];
#pragma unroll
    for (int j = 0; j < 32; j++) {
        half4v hv = *(const half4v*)(kv_t + ((size_t)((b * 32 + j) * 1024 + hw)) * 128 + 64 + vd);
        vreg[j] = (float4v){(float)hv.x, (float)hv.y, (float)hv.z, (float)hv.w};
    }
    _Float16* outb = o_t + (size_t)b * SS * 512;
#pragma unroll 2
    for (int rr = 0; rr < 128; rr++) {
        int row = half * 128 + rr;
        int hh = row >> 5, d = row & 31;
        const float* arow = &as_[row * 32];
        float ax = 0.f, ay = 0.f, az = 0.f, aw = 0.f;
#pragma unroll
        for (int j4 = 0; j4 < 8; j4++) {
            float4v a4 = *(const float4v*)(&arow[j4 * 4]);
            float4v v0 = vreg[j4 * 4 + 0];
            float4v v1 = vreg[j4 * 4 + 1];
            float4v v2 = vreg[j4 * 4 + 2];
            float4v v3 = vreg[j4 * 4 + 3];
            ax = fmaf(a4.x, v0.x, ax); ay = fmaf(a4.x, v0.y, ay);
            az = fmaf(a4.x, v0.z, az); aw = fmaf(a4.x, v0.w, aw);
            ax = fmaf(a4.y, v1.x, ax); ay = fmaf(a4.y, v1.y, ay);
            az = fmaf(a4.y, v1.z, az); aw = fmaf(a4.y, v1.w, aw);
            ax = fmaf(a4.z, v2.x, ax); ay = fmaf(a4.z, v2.y, ay);
            az = fmaf(a4.z, v2.z, az); aw = fmaf(a4.z, v2.w, aw);
            ax = fmaf(a4.w, v3.x, ax); ay = fmaf(a4.w, v3.y, ay);
            az = fmaf(a4.w, v3.z, az); aw = fmaf(a4.w, v3.w, aw);
        }
        int hp = hh * 4 + hl;
        size_t sp = (size_t)d * 1024 + hp * 32 + wq;
        half4v o4;
        o4.x = (_Float16)ax; o4.y = (_Float16)ay; o4.z = (_Float16)az; o4.w = (_Float16)aw;
        *(half4v*)(outb + sp * 512 + q4 * 4) = o4;
    }
}

// ---------------------------------------------------------------------------
// K5: proj GEMM via MFMA, BK=64, bank-swizzled LDS. + bias + layer_scale.
// XCD swizzle: 2 o_tiles of an s_tile share blockIdx%8.
// ---------------------------------------------------------------------------
__global__ __launch_bounds__(256)
void proj_mfma_kernel(const _Float16* __restrict__ o_t,
                      const _Float16* __restrict__ wp,
                      const float* __restrict__ pb,
                      const float* __restrict__ ls,
                      float* __restrict__ out)
{
    __shared__ _Float16 Ws[128 * 64];
    __shared__ _Float16 Xs[128 * 64];
    const int b = blockIdx.y;
    const int bx = blockIdx.x;
    const int grp = bx >> 4, rem = bx & 15;
    const int s_tile = grp * 8 + (rem & 7);
    const int o_tile = rem >> 3;
    const int s0 = s_tile * 128, o0 = o_tile * 128;
    const int t = threadIdx.x;
    const int w = t >> 6, l = t & 63;
    const int om = (w & 1) * 64, sn = (w >> 1) * 64;

    const int lr = l >> 3;
    const int gch = ((l & 7) - lr) & 7;
    const int m15 = l & 15;
    const int sl0 = ((((l >> 4) + (l & 7)) & 7)) * 8;
    const int sl1 = ((((l >> 4) + 4 + (l & 7)) & 7)) * 8;

    float4v acc[4][4];
#pragma unroll
    for (int i = 0; i < 4; i++)
#pragma unroll
        for (int j = 0; j < 4; j++) acc[i][j] = (float4v){0.f, 0.f, 0.f, 0.f};

    const _Float16* wg = wp + (size_t)(o0 + 32 * w + lr) * 512 + gch * 8;
    const _Float16* xg = o_t + ((size_t)b * SS + s0 + 32 * w + lr) * 512 + gch * 8;
    _Float16* wl = &Ws[(32 * w) * 64];
    _Float16* xl = &Xs[(32 * w) * 64];

    for (int c0 = 0; c0 < 512; c0 += 64) {
#pragma unroll
        for (int rb = 0; rb < 4; rb++) {
            gload16(wg + (size_t)rb * 8 * 512 + c0, wl + rb * 8 * 64);
            gload16(xg + (size_t)rb * 8 * 512 + c0, xl + rb * 8 * 64);
        }
        __syncthreads();
#pragma unroll
        for (int ks = 0; ks < 2; ks++) {
            const int sl = ks ? sl1 : sl0;
            half8v a[4], bb[4];
#pragma unroll
            for (int i = 0; i < 4; i++)
                a[i] = *(const half8v*)&Ws[(om + i * 16 + m15) * 64 + sl];
#pragma unroll
            for (int j = 0; j < 4; j++)
                bb[j] = *(const half8v*)&Xs[(sn + j * 16 + m15) * 64 + sl];
#pragma unroll
            for (int i = 0; i < 4; i++)
#pragma unroll
                for (int j = 0; j < 4; j++)
                    acc[i][j] = __builtin_amdgcn_mfma_f32_16x16x32_f16(a[i], bb[j], acc[i][j], 0, 0, 0);
        }
        __syncthreads();
    }
    const int qd = l >> 4, m = l & 15;
#pragma unroll
    for (int i = 0; i < 4; i++) {
        float pbv[4], lsv[4];
#pragma unroll
        for (int r = 0; r < 4; r++) {
            int o = o0 + om + i * 16 + qd * 4 + r;
            pbv[r] = pb[o];
            lsv[r] = ls[o];
        }
#pragma unroll
        for (int j = 0; j < 4; j++) {
            int s = s0 + sn + j * 16 + m;
#pragma unroll
            for (int r = 0; r < 4; r++) {
                int o = o0 + om + i * 16 + qd * 4 + r;
                out[((size_t)b * 256 + o) * SS + s] = (acc[i][j][r] + pbv[r]) * lsv[r];
            }
        }
    }
}

extern "C" void kernel_launch(void* const* d_in, const int* in_sizes, int n_in,
                              void* d_out, int out_size, void* d_ws, size_t ws_size,
                              hipStream_t stream)
{
    const float* x      = (const float*)d_in[0];
    const float* q_w    = (const float*)d_in[1];
    const float* q_b    = (const float*)d_in[2];
    const float* kv_w   = (const float*)d_in[3];
    const float* kv_b   = (const float*)d_in[4];
    const float* proj_w = (const float*)d_in[5];
    const float* proj_b = (const float*)d_in[6];
    const float* ls     = (const float*)d_in[7];
    float* out = (float*)d_out;

    char* ws = (char*)d_ws;
    _Float16* x_t  = (_Float16*)(ws);                        // 33,554,432 B
    _Float16* q_t  = (_Float16*)(ws + 33554432);             // 67,108,864 B (reused as o_t)
    _Float16* kv_t = (_Float16*)(ws + 100663296);            // 16,777,216 B
    float*    Lpart= (float*)   (ws + 117440512);            //  2,097,152 B
    float*    Lsm  = (float*)   (ws + 119537664);            //     65,536 B
    _Float16* wq   = (_Float16*)(ws + 119603200);            //    262,144 B
    _Float16* wkv  = (_Float16*)(ws + 119865344);            //     65,536 B
    _Float16* wp   = (_Float16*)(ws + 119930880);            //    262,144 B
    _Float16* o_t  = q_t;  // q dead after logits

    cvt_x_kernel<<<dim3(512, 4, 2), 256, 0, stream>>>(x, x_t);
    cvt_w3_kernel<<<dim3(288), 256, 0, stream>>>(q_w, wq, kv_w, wkv, proj_w, wp);

    conv_mfma_kernel<<<dim3(1280, 2), 256, 0, stream>>>(x_t, wq, wkv, q_b, kv_b, q_t, kv_t);
    logits_kernel<<<dim3(32, 8, 2), 256, 0, stream>>>(q_t, kv_t, Lpart);
    softmax_kernel<<<dim3(2), 256, 0, stream>>>(Lpart, Lsm);
    attn_v_kernel<<<dim3(32, 4, 2), 256, 0, stream>>>(kv_t, Lsm, o_t);
    proj_mfma_kernel<<<dim3(512, 2), 256, 0, stream>>>(o_t, wp, proj_b, ls, out);
}

// Round 4
// 265.096 us; speedup vs baseline: 1.0980x; 1.0980x over previous
//
#include <hip/hip_runtime.h>
#include <math.h>

#define SS 32768

typedef _Float16 half4v __attribute__((ext_vector_type(4)));
typedef _Float16 half8v __attribute__((ext_vector_type(8)));
typedef float float4v __attribute__((ext_vector_type(4)));

__device__ __forceinline__ void gload16(const void* g, void* l) {
    __builtin_amdgcn_global_load_lds(
        (const __attribute__((address_space(1))) unsigned int*)g,
        (__attribute__((address_space(3))) unsigned int*)l, 16, 0, 0);
}

// ---------------------------------------------------------------------------
// K0a: x[b][c][s] fp32 -> x_t[b][s][c] fp16 (LDS tile transpose)
// ---------------------------------------------------------------------------
__global__ __launch_bounds__(256)
void cvt_x_kernel(const float* __restrict__ x, _Float16* __restrict__ x_t)
{
    __shared__ float ls[64][65];
    const int b = blockIdx.z, c0 = blockIdx.y * 64, s0 = blockIdx.x * 64;
    const int t = threadIdx.x;
    const int tr = t >> 4, tc = t & 15;
#pragma unroll
    for (int p = 0; p < 4; p++) {
        int c_l = p * 16 + tr;
        float4v v = *(const float4v*)(x + (size_t)(b * 256 + c0 + c_l) * SS + s0 + tc * 4);
        ls[c_l][tc * 4 + 0] = v.x;
        ls[c_l][tc * 4 + 1] = v.y;
        ls[c_l][tc * 4 + 2] = v.z;
        ls[c_l][tc * 4 + 3] = v.w;
    }
    __syncthreads();
#pragma unroll
    for (int p = 0; p < 4; p++) {
        int s_l = p * 16 + tr;
        half4v h;
        h.x = (_Float16)ls[tc * 4 + 0][s_l];
        h.y = (_Float16)ls[tc * 4 + 1][s_l];
        h.z = (_Float16)ls[tc * 4 + 2][s_l];
        h.w = (_Float16)ls[tc * 4 + 3][s_l];
        *(half4v*)(x_t + ((size_t)b * SS + s0 + s_l) * 256 + c0 + tc * 4) = h;
    }
}

// ---------------------------------------------------------------------------
// K0b: all three weight casts in one launch.
// ---------------------------------------------------------------------------
__global__ __launch_bounds__(256)
void cvt_w3_kernel(const float* __restrict__ s0, _Float16* __restrict__ d0,
                   const float* __restrict__ s1, _Float16* __restrict__ d1,
                   const float* __restrict__ s2, _Float16* __restrict__ d2)
{
    int bx = blockIdx.x;
    const float* s; _Float16* d; int base;
    if (bx < 128)      { s = s0; d = d0; base = bx; }
    else if (bx < 160) { s = s1; d = d1; base = bx - 128; }
    else               { s = s2; d = d2; base = bx - 160; }
    int i = (base * 256 + threadIdx.x) * 4;
    float4v v = *(const float4v*)(s + i);
    half4v h;
    h.x = (_Float16)v.x; h.y = (_Float16)v.y; h.z = (_Float16)v.z; h.w = (_Float16)v.w;
    *(half4v*)(d + i) = h;
}

// ---------------------------------------------------------------------------
// K1: fused q+kv conv via MFMA, BK=64, swizzled staging, LDS-staged epilogue.
// out_t[b,s,o] = sum_c W[o,c]*x_t[b,s,c] + bias.  128(o) x 128(s) tile.
// XCD swizzle: 5 o_tiles of one s_tile share blockIdx%8 -> x-tile L2 reuse.
// Epilogue: acc -> LDS T[128s][136] fp16 (16B-aligned rows), then coalesced
// 16B stores (16 lanes x 16B = 256B contiguous per s-row). Fixes the 1.6x
// write amplification seen in R3 (WRITE_SIZE 126MB vs 80MB ideal).
// ---------------------------------------------------------------------------
__global__ __launch_bounds__(256)
void conv_mfma_kernel(const _Float16* __restrict__ x_t,
                      const _Float16* __restrict__ wq,
                      const _Float16* __restrict__ wkv,
                      const float* __restrict__ q_b,
                      const float* __restrict__ kv_b,
                      _Float16* __restrict__ q_t,
                      _Float16* __restrict__ kv_t)
{
    __shared__ _Float16 smem[128 * 136];          // 34816 B; aliases staging+epilogue
    _Float16* const Ws = smem;                    // [128][64] staging
    _Float16* const Xs = smem + 128 * 64;         // [128][64] staging
    const int b = blockIdx.y;
    const int bx = blockIdx.x;
    const int grp = bx / 40, rem = bx % 40;
    const int s_tile = grp * 8 + (rem & 7);
    const int o_tile = rem >> 3;
    const int s0 = s_tile * 128;
    const bool is_q = (o_tile < 4);
    const _Float16* W = is_q ? wq : wkv;
    const float* bias = is_q ? q_b : kv_b;
    const int od0 = is_q ? o_tile * 128 : 0;
    const int ODST = is_q ? 512 : 128;
    _Float16* dst = is_q ? q_t : kv_t;

    const int t = threadIdx.x;
    const int w = t >> 6, l = t & 63;
    const int om = (w & 1) * 64, sn = (w >> 1) * 64;

    const int lr = l >> 3;                       // staging row within 8-row group
    const int gch = ((l & 7) - lr) & 7;          // global chunk this lane stages
    const int m15 = l & 15;
    const int sl0 = ((((l >> 4) + (l & 7)) & 7)) * 8;      // read slot, ks=0
    const int sl1 = ((((l >> 4) + 4 + (l & 7)) & 7)) * 8;  // read slot, ks=1

    float4v acc[4][4];
#pragma unroll
    for (int i = 0; i < 4; i++)
#pragma unroll
        for (int j = 0; j < 4; j++) acc[i][j] = (float4v){0.f, 0.f, 0.f, 0.f};

    const _Float16* wg = W + (size_t)(od0 + 32 * w + lr) * 256 + gch * 8;
    const _Float16* xg = x_t + ((size_t)b * SS + s0 + 32 * w + lr) * 256 + gch * 8;
    _Float16* wl = &Ws[(32 * w) * 64];
    _Float16* xl = &Xs[(32 * w) * 64];

    for (int c0 = 0; c0 < 256; c0 += 64) {
#pragma unroll
        for (int rb = 0; rb < 4; rb++) {
            gload16(wg + (size_t)rb * 8 * 256 + c0, wl + rb * 8 * 64);
            gload16(xg + (size_t)rb * 8 * 256 + c0, xl + rb * 8 * 64);
        }
        __syncthreads();
#pragma unroll
        for (int ks = 0; ks < 2; ks++) {
            const int sl = ks ? sl1 : sl0;
            half8v a[4], bb[4];
#pragma unroll
            for (int i = 0; i < 4; i++)
                a[i] = *(const half8v*)&Ws[(om + i * 16 + m15) * 64 + sl];
#pragma unroll
            for (int j = 0; j < 4; j++)
                bb[j] = *(const half8v*)&Xs[(sn + j * 16 + m15) * 64 + sl];
#pragma unroll
            for (int i = 0; i < 4; i++)
#pragma unroll
                for (int j = 0; j < 4; j++)
                    acc[i][j] = __builtin_amdgcn_mfma_f32_16x16x32_f16(a[i], bb[j], acc[i][j], 0, 0, 0);
        }
        __syncthreads();
    }
    // ---- epilogue: stage into T[s][136] fp16, then coalesced global stores
    const int qd = l >> 4, m = l & 15;
#pragma unroll
    for (int i = 0; i < 4; i++) {
        float bv[4];
#pragma unroll
        for (int r = 0; r < 4; r++) bv[r] = bias[od0 + om + i * 16 + qd * 4 + r];
#pragma unroll
        for (int j = 0; j < 4; j++) {
            half4v h;
            h.x = (_Float16)(acc[i][j].x + bv[0]);
            h.y = (_Float16)(acc[i][j].y + bv[1]);
            h.z = (_Float16)(acc[i][j].z + bv[2]);
            h.w = (_Float16)(acc[i][j].w + bv[3]);
            int s_l = sn + j * 16 + m;
            *(half4v*)&smem[s_l * 136 + om + i * 16 + qd * 4] = h;
        }
    }
    __syncthreads();
    const int sr = t >> 4, kk = t & 15;
#pragma unroll
    for (int p = 0; p < 8; p++) {
        int s_l = p * 16 + sr;
        half8v h8 = *(const half8v*)&smem[s_l * 136 + kk * 8];
        *(half8v*)(dst + ((size_t)b * SS + s0 + s_l) * ODST + od0 + kk * 8) = h8;
    }
}

// ---------------------------------------------------------------------------
// K2: logits, direct-global MFMA fragments (coalesced at 64B granularity),
// no K-loop barriers. Partial 32x32 tiles -> Lpart[hwc][b][nh].
// ---------------------------------------------------------------------------
__global__ __launch_bounds__(256)
void logits_kernel(const _Float16* __restrict__ q_t,
                   const _Float16* __restrict__ kv_t,
                   float* __restrict__ Lpart)
{
    __shared__ float red[4][1024];
    const int hwc = blockIdx.x, nh = blockIdx.y, b = blockIdx.z;
    const int t = threadIdx.x, w = t >> 6, l = t & 63;
    const int m = l & 15, c8 = (l >> 4) * 8;
    float4v acc[2][2];
#pragma unroll
    for (int i = 0; i < 2; i++)
#pragma unroll
        for (int j = 0; j < 2; j++) acc[i][j] = (float4v){0.f, 0.f, 0.f, 0.f};

    const _Float16* qb0 = q_t + (size_t)b * SS * 512 + nh * 64 + c8;
    const _Float16* kb0 = kv_t + (size_t)b * SS * 128 + c8;
#pragma unroll 4
    for (int hh = 0; hh < 8; hh++) {
        const int hw = hwc * 32 + w * 8 + hh;
        const _Float16* qr0 = qb0 + ((size_t)m * 1024 + hw) * 512;
        const _Float16* qr1 = qb0 + ((size_t)(m + 16) * 1024 + hw) * 512;
        const _Float16* kr0 = kb0 + ((size_t)m * 1024 + hw) * 128;
        const _Float16* kr1 = kb0 + ((size_t)(m + 16) * 1024 + hw) * 128;
        half8v a0l = *(const half8v*)(qr0);
        half8v a0h = *(const half8v*)(qr0 + 32);
        half8v a1l = *(const half8v*)(qr1);
        half8v a1h = *(const half8v*)(qr1 + 32);
        half8v b0l = *(const half8v*)(kr0);
        half8v b0h = *(const half8v*)(kr0 + 32);
        half8v b1l = *(const half8v*)(kr1);
        half8v b1h = *(const half8v*)(kr1 + 32);
        acc[0][0] = __builtin_amdgcn_mfma_f32_16x16x32_f16(a0l, b0l, acc[0][0], 0, 0, 0);
        acc[0][0] = __builtin_amdgcn_mfma_f32_16x16x32_f16(a0h, b0h, acc[0][0], 0, 0, 0);
        acc[0][1] = __builtin_amdgcn_mfma_f32_16x16x32_f16(a0l, b1l, acc[0][1], 0, 0, 0);
        acc[0][1] = __builtin_amdgcn_mfma_f32_16x16x32_f16(a0h, b1h, acc[0][1], 0, 0, 0);
        acc[1][0] = __builtin_amdgcn_mfma_f32_16x16x32_f16(a1l, b0l, acc[1][0], 0, 0, 0);
        acc[1][0] = __builtin_amdgcn_mfma_f32_16x16x32_f16(a1h, b0h, acc[1][0], 0, 0, 0);
        acc[1][1] = __builtin_amdgcn_mfma_f32_16x16x32_f16(a1l, b1l, acc[1][1], 0, 0, 0);
        acc[1][1] = __builtin_amdgcn_mfma_f32_16x16x32_f16(a1h, b1h, acc[1][1], 0, 0, 0);
    }
    const int rbase = (l >> 4) * 4;
#pragma unroll
    for (int qi = 0; qi < 2; qi++)
#pragma unroll
        for (int qj = 0; qj < 2; qj++)
#pragma unroll
            for (int rr = 0; rr < 4; rr++)
                red[w][(qi * 16 + rbase + rr) * 32 + qj * 16 + m] = acc[qi][qj][rr];
    __syncthreads();
    float4v v = *(const float4v*)&red[0][t * 4];
    v += *(const float4v*)&red[1][t * 4];
    v += *(const float4v*)&red[2][t * 4];
    v += *(const float4v*)&red[3][t * 4];
    *(float4v*)(Lpart + (((size_t)hwc * 2 + b) * 8 + nh) * 1024 + t * 4) = v;
}

// ---------------------------------------------------------------------------
// K3: reduce 32 hwc partials + softmax (scale 0.125), write dense Lsm.
// ---------------------------------------------------------------------------
__global__ __launch_bounds__(256)
void softmax_kernel(const float* __restrict__ Lpart, float* __restrict__ Lsm)
{
    int r = blockIdx.x * 256 + threadIdx.x;   // 0..511 = (b, nh, d)
    float4v p[8];
#pragma unroll
    for (int j4 = 0; j4 < 8; j4++) p[j4] = (float4v){0.f, 0.f, 0.f, 0.f};
    for (int hwc = 0; hwc < 32; hwc++) {
        const float* src = Lpart + (size_t)hwc * 16384 + (size_t)r * 32;
#pragma unroll
        for (int j4 = 0; j4 < 8; j4++) p[j4] += *(const float4v*)(src + j4 * 4);
    }
    float mx = p[0].x;
#pragma unroll
    for (int j4 = 0; j4 < 8; j4++) {
        mx = fmaxf(mx, p[j4].x); mx = fmaxf(mx, p[j4].y);
        mx = fmaxf(mx, p[j4].z); mx = fmaxf(mx, p[j4].w);
    }
    float s = 0.f;
#pragma unroll
    for (int j4 = 0; j4 < 8; j4++) {
        p[j4].x = expf((p[j4].x - mx) * 0.125f); s += p[j4].x;
        p[j4].y = expf((p[j4].y - mx) * 0.125f); s += p[j4].y;
        p[j4].z = expf((p[j4].z - mx) * 0.125f); s += p[j4].z;
        p[j4].w = expf((p[j4].w - mx) * 0.125f); s += p[j4].w;
    }
    float inv = 1.f / s;
    float* dst = Lsm + (size_t)r * 32;
#pragma unroll
    for (int j4 = 0; j4 < 8; j4++) {
        float4v o = p[j4];
        o.x *= inv; o.y *= inv; o.z *= inv; o.w *= inv;
        *(float4v*)(dst + j4 * 4) = o;
    }
}

// ---------------------------------------------------------------------------
// K4: o_t[b, s'=(d,h,w), c'] = sum_j attn[b, h>>2, d, j]
//        * kv_t[b, j, (h&3)*256 + w*8 + (c'>>6), 64+(c'&63)]
// grid 1024 blocks (wq, hl, b*4+rc); each block: 64 rows, 8KB attn slice.
// 4 blocks/CU (was 1) to hide fma/LDS latency.
// ---------------------------------------------------------------------------
__global__ __launch_bounds__(256)
void attn_v_kernel(const _Float16* __restrict__ kv_t,
                   const float* __restrict__ attn,
                   _Float16* __restrict__ o_t)
{
    __shared__ float as_[2048];
    const int wq = blockIdx.x, hl = blockIdx.y;
    const int b = blockIdx.z >> 2, rc = blockIdx.z & 3;
    const int t = threadIdx.x;
    {
        const float* src = attn + (size_t)b * 8192 + rc * 2048;
#pragma unroll
        for (int ll = 0; ll < 2; ll++) {
            int idx = (t + ll * 256) * 4;
            *(float4v*)(&as_[idx]) = *(const float4v*)(src + idx);
        }
    }
    __syncthreads();
    const int q4 = t & 127;
    const int half = t >> 7;
    const int tt = q4 >> 4;
    const int vd = (q4 * 4) & 63;
    const int hw = hl * 256 + wq * 8 + tt;
    float4v vreg[32];
#pragma unroll
    for (int j = 0; j < 32; j++) {
        half4v hv = *(const half4v*)(kv_t + ((size_t)((b * 32 + j) * 1024 + hw)) * 128 + 64 + vd);
        vreg[j] = (float4v){(float)hv.x, (float)hv.y, (float)hv.z, (float)hv.w};
    }
    _Float16* outb = o_t + (size_t)b * SS * 512;
#pragma unroll 2
    for (int rr = 0; rr < 32; rr++) {
        int row_l = half * 32 + rr;          // 0..63 within slice
        int row = rc * 64 + row_l;           // nh*32 + d
        int hh = row >> 5, d = row & 31;
        const float* arow = &as_[row_l * 32];
        float ax = 0.f, ay = 0.f, az = 0.f, aw = 0.f;
#pragma unroll
        for (int j4 = 0; j4 < 8; j4++) {
            float4v a4 = *(const float4v*)(&arow[j4 * 4]);
            float4v v0 = vreg[j4 * 4 + 0];
            float4v v1 = vreg[j4 * 4 + 1];
            float4v v2 = vreg[j4 * 4 + 2];
            float4v v3 = vreg[j4 * 4 + 3];
            ax = fmaf(a4.x, v0.x, ax); ay = fmaf(a4.x, v0.y, ay);
            az = fmaf(a4.x, v0.z, az); aw = fmaf(a4.x, v0.w, aw);
            ax = fmaf(a4.y, v1.x, ax); ay = fmaf(a4.y, v1.y, ay);
            az = fmaf(a4.y, v1.z, az); aw = fmaf(a4.y, v1.w, aw);
            ax = fmaf(a4.z, v2.x, ax); ay = fmaf(a4.z, v2.y, ay);
            az = fmaf(a4.z, v2.z, az); aw = fmaf(a4.z, v2.w, aw);
            ax = fmaf(a4.w, v3.x, ax); ay = fmaf(a4.w, v3.y, ay);
            az = fmaf(a4.w, v3.z, az); aw = fmaf(a4.w, v3.w, aw);
        }
        int hp = hh * 4 + hl;
        size_t sp = (size_t)d * 1024 + hp * 32 + wq;
        half4v o4;
        o4.x = (_Float16)ax; o4.y = (_Float16)ay; o4.z = (_Float16)az; o4.w = (_Float16)aw;
        *(half4v*)(outb + sp * 512 + q4 * 4) = o4;
    }
}

// ---------------------------------------------------------------------------
// K5: proj GEMM via MFMA, BK=64, bank-swizzled LDS. + bias + layer_scale.
// ---------------------------------------------------------------------------
__global__ __launch_bounds__(256)
void proj_mfma_kernel(const _Float16* __restrict__ o_t,
                      const _Float16* __restrict__ wp,
                      const float* __restrict__ pb,
                      const float* __restrict__ ls,
                      float* __restrict__ out)
{
    __shared__ _Float16 Ws[128 * 64];
    __shared__ _Float16 Xs[128 * 64];
    const int b = blockIdx.y;
    const int bx = blockIdx.x;
    const int grp = bx >> 4, rem = bx & 15;
    const int s_tile = grp * 8 + (rem & 7);
    const int o_tile = rem >> 3;
    const int s0 = s_tile * 128, o0 = o_tile * 128;
    const int t = threadIdx.x;
    const int w = t >> 6, l = t & 63;
    const int om = (w & 1) * 64, sn = (w >> 1) * 64;

    const int lr = l >> 3;
    const int gch = ((l & 7) - lr) & 7;
    const int m15 = l & 15;
    const int sl0 = ((((l >> 4) + (l & 7)) & 7)) * 8;
    const int sl1 = ((((l >> 4) + 4 + (l & 7)) & 7)) * 8;

    float4v acc[4][4];
#pragma unroll
    for (int i = 0; i < 4; i++)
#pragma unroll
        for (int j = 0; j < 4; j++) acc[i][j] = (float4v){0.f, 0.f, 0.f, 0.f};

    const _Float16* wg = wp + (size_t)(o0 + 32 * w + lr) * 512 + gch * 8;
    const _Float16* xg = o_t + ((size_t)b * SS + s0 + 32 * w + lr) * 512 + gch * 8;
    _Float16* wl = &Ws[(32 * w) * 64];
    _Float16* xl = &Xs[(32 * w) * 64];

    for (int c0 = 0; c0 < 512; c0 += 64) {
#pragma unroll
        for (int rb = 0; rb < 4; rb++) {
            gload16(wg + (size_t)rb * 8 * 512 + c0, wl + rb * 8 * 64);
            gload16(xg + (size_t)rb * 8 * 512 + c0, xl + rb * 8 * 64);
        }
        __syncthreads();
#pragma unroll
        for (int ks = 0; ks < 2; ks++) {
            const int sl = ks ? sl1 : sl0;
            half8v a[4], bb[4];
#pragma unroll
            for (int i = 0; i < 4; i++)
                a[i] = *(const half8v*)&Ws[(om + i * 16 + m15) * 64 + sl];
#pragma unroll
            for (int j = 0; j < 4; j++)
                bb[j] = *(const half8v*)&Xs[(sn + j * 16 + m15) * 64 + sl];
#pragma unroll
            for (int i = 0; i < 4; i++)
#pragma unroll
                for (int j = 0; j < 4; j++)
                    acc[i][j] = __builtin_amdgcn_mfma_f32_16x16x32_f16(a[i], bb[j], acc[i][j], 0, 0, 0);
        }
        __syncthreads();
    }
    const int qd = l >> 4, m = l & 15;
#pragma unroll
    for (int i = 0; i < 4; i++) {
        float pbv[4], lsv[4];
#pragma unroll
        for (int r = 0; r < 4; r++) {
            int o = o0 + om + i * 16 + qd * 4 + r;
            pbv[r] = pb[o];
            lsv[r] = ls[o];
        }
#pragma unroll
        for (int j = 0; j < 4; j++) {
            int s = s0 + sn + j * 16 + m;
#pragma unroll
            for (int r = 0; r < 4; r++) {
                int o = o0 + om + i * 16 + qd * 4 + r;
                out[((size_t)b * 256 + o) * SS + s] = (acc[i][j][r] + pbv[r]) * lsv[r];
            }
        }
    }
}

extern "C" void kernel_launch(void* const* d_in, const int* in_sizes, int n_in,
                              void* d_out, int out_size, void* d_ws, size_t ws_size,
                              hipStream_t stream)
{
    const float* x      = (const float*)d_in[0];
    const float* q_w    = (const float*)d_in[1];
    const float* q_b    = (const float*)d_in[2];
    const float* kv_w   = (const float*)d_in[3];
    const float* kv_b   = (const float*)d_in[4];
    const float* proj_w = (const float*)d_in[5];
    const float* proj_b = (const float*)d_in[6];
    const float* ls     = (const float*)d_in[7];
    float* out = (float*)d_out;

    char* ws = (char*)d_ws;
    _Float16* x_t  = (_Float16*)(ws);                        // 33,554,432 B
    _Float16* q_t  = (_Float16*)(ws + 33554432);             // 67,108,864 B (reused as o_t)
    _Float16* kv_t = (_Float16*)(ws + 100663296);            // 16,777,216 B
    float*    Lpart= (float*)   (ws + 117440512);            //  2,097,152 B
    float*    Lsm  = (float*)   (ws + 119537664);            //     65,536 B
    _Float16* wq   = (_Float16*)(ws + 119603200);            //    262,144 B
    _Float16* wkv  = (_Float16*)(ws + 119865344);            //     65,536 B
    _Float16* wp   = (_Float16*)(ws + 119930880);            //    262,144 B
    _Float16* o_t  = q_t;  // q dead after logits

    cvt_x_kernel<<<dim3(512, 4, 2), 256, 0, stream>>>(x, x_t);
    cvt_w3_kernel<<<dim3(288), 256, 0, stream>>>(q_w, wq, kv_w, wkv, proj_w, wp);

    conv_mfma_kernel<<<dim3(1280, 2), 256, 0, stream>>>(x_t, wq, wkv, q_b, kv_b, q_t, kv_t);
    logits_kernel<<<dim3(32, 8, 2), 256, 0, stream>>>(q_t, kv_t, Lpart);
    softmax_kernel<<<dim3(2), 256, 0, stream>>>(Lpart, Lsm);
    attn_v_kernel<<<dim3(32, 4, 8), 256, 0, stream>>>(kv_t, Lsm, o_t);
    proj_mfma_kernel<<<dim3(512, 2), 256, 0, stream>>>(o_t, wp, proj_b, ls, out);
}